// Round 2
// baseline (288.070 us; speedup 1.0000x reference)
//
#include <hip/hip_runtime.h>

// GAGKNNQueryAndGroup: B=4, N=8192, NPOINT=2048, C=64, NSAMPLE=32, LAMBDA=0.5
// LAMBDA == 0.5 makes the component mask numerically irrelevant:
// where(mask, d*0.5, d*0.5) == d*0.5 (exact, order-preserving). Components unused.

#define BQ 4
#define NN_ 8192
#define NPOINT 2048
#define CF 64
#define NS 32
#define QB 8           // queries per block
#define CHUNK 2048     // points staged in LDS per iteration
#define CAP 768        // candidate capacity per query (E[m]~130, max~600)

// ---------------- Phase 1: exact top-32 selection, 8 queries/block ----------------
__global__ __launch_bounds__(256, 3) void knn_kernel(const float* __restrict__ xyz,
                                                     const float* __restrict__ new_xyz,
                                                     int* __restrict__ idxOut) {
  const int tid = threadIdx.x;
  const int g = tid >> 5;      // query slot 0..7
  const int s = tid & 31;      // scan lane 0..31
  const int q = blockIdx.x * QB + g;
  const int b = q / NPOINT;

  // stage (pass 1) and cand (pass 2) never live at the same time -> union
  __shared__ union {
    float stage[CHUNK * 3];                    // 24 KB
    unsigned long long cand[QB][CAP];          // 48 KB
  } sh;
  __shared__ int cnt[QB];

  const float qx = new_xyz[q * 3 + 0];
  const float qy = new_xyz[q * 3 + 1];
  const float qz = new_xyz[q * 3 + 2];
  const float* __restrict__ base = xyz + (size_t)b * NN_ * 3;

  // ---- pass 1: per-lane min over its stride-32 partition, xyz via LDS ----
  float lmin = 3.4e38f;
  for (int c0 = 0; c0 < NN_; c0 += CHUNK) {
    __syncthreads();
    {
      const float4* src = (const float4*)(base + (size_t)c0 * 3);
      float4* dst = (float4*)sh.stage;
#pragma unroll
      for (int k = 0; k < (CHUNK * 3 / 4) / 256; k++)
        dst[tid + k * 256] = src[tid + k * 256];
    }
    __syncthreads();
#pragma unroll 8
    for (int j = 0; j < CHUNK / 32; j++) {
      int p = s + j * 32;
      // exact numpy f32 semantics: no FMA contraction, left-to-right sum
      float dx = sh.stage[p * 3 + 0] - qx;
      float dy = sh.stage[p * 3 + 1] - qy;
      float dz = sh.stage[p * 3 + 2] - qz;
      float dist = __fadd_rn(__fadd_rn(__fmul_rn(dx, dx), __fmul_rn(dy, dy)),
                             __fmul_rn(dz, dz));
      dist *= 0.5f;   // LAMBDA == 1-LAMBDA == 0.5, exact
      lmin = fminf(lmin, dist);
    }
  }

  // theta = max of the 32 lane-minima of this query: guaranteed >= true 32nd
  // smallest (the 32 lane minima are 32 distinct data values <= theta).
  // masks <32 keep the butterfly inside each 32-lane half of the wave.
  float th = lmin;
#pragma unroll
  for (int mask = 16; mask >= 1; mask >>= 1)
    th = fmaxf(th, __shfl_xor(th, mask));

  __syncthreads();              // stage reads done; union becomes cand
  if (tid < QB) cnt[tid] = 0;
  __syncthreads();

  // ---- pass 2: recompute (bit-identical), collect d <= theta ----
#pragma unroll 4
  for (int j = 0; j < NN_ / 32; j++) {
    int p = s + j * 32;
    float dx = base[p * 3 + 0] - qx;
    float dy = base[p * 3 + 1] - qy;
    float dz = base[p * 3 + 2] - qz;
    float dist = __fadd_rn(__fadd_rn(__fmul_rn(dx, dx), __fmul_rn(dy, dy)),
                           __fmul_rn(dz, dz));
    dist *= 0.5f;
    if (dist <= th) {
      int pos = atomicAdd(&cnt[g], 1);
      if (pos < CAP)
        sh.cand[g][pos] =
            ((unsigned long long)__float_as_uint(dist) << 32) | (unsigned)p;
    }
  }
  __syncthreads();
  const int m = cnt[g] < CAP ? cnt[g] : CAP;

  // ---- exact rank by (dist_bits, idx) == stable argsort order ----
  for (int b0 = 0; b0 < m; b0 += 64) {
    unsigned long long x0 = (b0 + s < m) ? sh.cand[g][b0 + s] : ~0ull;
    unsigned long long x1 = (b0 + 32 + s < m) ? sh.cand[g][b0 + 32 + s] : ~0ull;
    int r0 = 0, r1 = 0;
    for (int j = 0; j < m; j++) {
      unsigned long long cj = sh.cand[g][j];   // broadcast read
      r0 += (cj < x0) ? 1 : 0;
      r1 += (cj < x1) ? 1 : 0;
    }
    if (b0 + s < m && r0 < NS) idxOut[(size_t)q * NS + r0] = (int)(unsigned)x0;
    if (b0 + 32 + s < m && r1 < NS) idxOut[(size_t)q * NS + r1] = (int)(unsigned)x1;
  }
}

// ---------------- Phase 2: features (B,C,N) -> featsT (B,N,C) ----------------
__global__ __launch_bounds__(256) void transpose_kernel(const float* __restrict__ f,
                                                        float* __restrict__ ft) {
  __shared__ float t[32][33];
  const int b = blockIdx.z;
  const int n0 = blockIdx.x * 32;
  const int c0 = blockIdx.y * 32;
  const int tx = threadIdx.x;   // 0..31
  const int ty = threadIdx.y;   // 0..7
#pragma unroll
  for (int i = 0; i < 4; i++) {
    int c = c0 + ty + i * 8;
    t[ty + i * 8][tx] = f[(size_t)b * CF * NN_ + (size_t)c * NN_ + n0 + tx];
  }
  __syncthreads();
#pragma unroll
  for (int i = 0; i < 4; i++) {
    int nrow = n0 + ty + i * 8;
    ft[(size_t)b * NN_ * CF + (size_t)nrow * CF + c0 + tx] = t[tx][ty + i * 8];
  }
}

// ---------------- Phase 3: gather + grouped write ----------------
#define FSTR 68   // LDS row stride: multiple of 4 (float4 stores), 4-way alias max
__global__ __launch_bounds__(256) void group_kernel(const float* __restrict__ xyz,
                                                    const float* __restrict__ new_xyz,
                                                    const float* __restrict__ featsT,
                                                    const int* __restrict__ idxArr,
                                                    float* __restrict__ out) {
  const int q = blockIdx.x;            // b*NPOINT + p
  const int b = q / NPOINT;
  const int p = q - b * NPOINT;
  const int tid = threadIdx.x;

  __shared__ int sIdx[NS];
  __shared__ __align__(16) float ldsF[NS * FSTR];
  __shared__ float ldsX[3 * NS];

  if (tid < NS) sIdx[tid] = idxArr[q * NS + tid];
  __syncthreads();

  {
    // 256 threads = 32 samples x 8 readers; each reader pulls 32B of the
    // 256B contiguous feature row for its sample.
    int s = tid >> 3, r = tid & 7;
    int nn = sIdx[s];
    const float4* src = (const float4*)(featsT + ((size_t)b * NN_ + nn) * CF);
    float4 v0 = src[r * 2];
    float4 v1 = src[r * 2 + 1];
    float4* dst = (float4*)(ldsF + s * FSTR + r * 8);
    dst[0] = v0;
    dst[1] = v1;
  }
  if (tid < 96) {
    int dd = tid >> 5, s = tid & 31;
    int nn = sIdx[s];
    ldsX[dd * NS + s] = xyz[((size_t)b * NN_ + nn) * 3 + dd] -
                        new_xyz[(size_t)q * 3 + dd];
  }
  __syncthreads();

  // Write 67 rows of 32 floats (128B coalesced per row), 8 rows at a time.
  const int s = tid & 31;
  const int r0 = tid >> 5;
#pragma unroll
  for (int k = 0; k < 9; k++) {
    int row = r0 + k * 8;
    if (row < 67) {
      float v = (row < 3) ? ldsX[row * NS + s] : ldsF[s * FSTR + (row - 3)];
      out[(((size_t)b * 67 + row) * NPOINT + p) * NS + s] = v;
    }
  }
}

extern "C" void kernel_launch(void* const* d_in, const int* in_sizes, int n_in,
                              void* d_out, int out_size, void* d_ws, size_t ws_size,
                              hipStream_t stream) {
  const float* xyz      = (const float*)d_in[0];   // (4,8192,3)
  const float* new_xyz  = (const float*)d_in[1];   // (4,2048,3)
  // d_in[2], d_in[3]: components — unused (LAMBDA=0.5 makes mask a no-op)
  const float* features = (const float*)d_in[4];   // (4,64,8192)
  float* out = (float*)d_out;

  // workspace: [idx: 4*2048*32 int = 1MB][featsT: 4*8192*64 f32 = 8MB]
  int* idxArr = (int*)d_ws;
  float* featsT = (float*)((char*)d_ws + (size_t)BQ * NPOINT * NS * sizeof(int));

  knn_kernel<<<(BQ * NPOINT) / QB, 256, 0, stream>>>(xyz, new_xyz, idxArr);
  transpose_kernel<<<dim3(NN_ / 32, CF / 32, BQ), dim3(32, 8), 0, stream>>>(features, featsT);
  group_kernel<<<BQ * NPOINT, 256, 0, stream>>>(xyz, new_xyz, featsT, idxArr, out);
}

// Round 3
// 175.362 us; speedup vs baseline: 1.6427x; 1.6427x over previous
//
#include <hip/hip_runtime.h>

// GAGKNNQueryAndGroup: B=4, N=8192, NPOINT=2048, C=64, NSAMPLE=32, LAMBDA=0.5
// LAMBDA == 0.5 makes the component mask numerically irrelevant:
// where(mask, d*0.5, d*0.5) == d*0.5 (exact, order-preserving). Components unused.

#define BQ 4
#define NN_ 8192
#define NPOINT 2048
#define CF 64
#define NS 32
#define CAP 512   // candidate capacity (E[m]~170 from 4 per-wave thetas)

// ---------------- Phase 1: exact top-32 selection per query ----------------
// 1 query / 256-thread block. Single data pass; d[32] kept in VGPRs
// (launch_bounds(256,3) -> 170 VGPR cap, no spill). Theta per wave via
// register bitonic sort of the 64 lane-minima (no LDS, no barriers).
__global__ __launch_bounds__(256, 3) void knn_kernel(const float* __restrict__ xyz,
                                                     const float* __restrict__ new_xyz,
                                                     int* __restrict__ idxOut) {
  const int q = blockIdx.x;            // b*NPOINT + p
  const int b = q >> 11;               // q / NPOINT
  const int tid = threadIdx.x;

  const float qx = new_xyz[q * 3 + 0];
  const float qy = new_xyz[q * 3 + 1];
  const float qz = new_xyz[q * 3 + 2];

  const float4* __restrict__ X4 = (const float4*)(xyz + (size_t)b * NN_ * 3);

  // Thread t covers points {4t+i + 1024*jc : jc in 0..7, i in 0..3}.
  // 3 float4 loads per chunk = 48B contiguous per lane, fully coalesced.
  float d[32];
  float lmin = 3.4e38f;
#pragma unroll
  for (int jc = 0; jc < 8; jc++) {
    float4 a0 = X4[3 * tid + 768 * jc + 0];
    float4 a1 = X4[3 * tid + 768 * jc + 1];
    float4 a2 = X4[3 * tid + 768 * jc + 2];
    float px[4] = {a0.x, a0.w, a1.z, a2.y};
    float py[4] = {a0.y, a1.x, a1.w, a2.z};
    float pz[4] = {a0.z, a1.y, a2.x, a2.w};
#pragma unroll
    for (int i = 0; i < 4; i++) {
      // exact numpy f32 semantics: no FMA contraction, left-to-right sum
      float dx = px[i] - qx;
      float dy = py[i] - qy;
      float dz = pz[i] - qz;
      float dist = __fadd_rn(__fadd_rn(__fmul_rn(dx, dx), __fmul_rn(dy, dy)),
                             __fmul_rn(dz, dz));
      dist *= 0.5f;   // LAMBDA == 1-LAMBDA == 0.5, exact
      d[jc * 4 + i] = dist;
      lmin = fminf(lmin, dist);
    }
  }

  // Per-wave theta: bitonic-sort the 64 lane minima in registers; theta_w =
  // 32nd smallest (lane 31). The 32 smallest lane-minima are 32 distinct data
  // values <= theta_w, so theta_w >= true 32nd-smallest distance -> every
  // true top-32 point (in any wave's partition) satisfies d <= theta of its
  // own wave. Union over waves of {d <= theta_w} contains the true top-32.
  {
    const int lane = tid & 63;
    float v = lmin;
#pragma unroll
    for (int k = 2; k <= 64; k <<= 1) {
#pragma unroll
      for (int j = k >> 1; j > 0; j >>= 1) {
        float o = __shfl_xor(v, j);
        bool dirUp = ((lane & k) == 0);
        bool lower = ((lane & j) == 0);
        float mn = fminf(v, o), mx = fmaxf(v, o);
        v = (dirUp == lower) ? mn : mx;
      }
    }
    lmin = __shfl(v, 31);   // reuse lmin as theta_w (uniform per wave)
  }
  const float theta = lmin;

  __shared__ unsigned long long cand[CAP];
  __shared__ int cnt;
  if (tid == 0) cnt = 0;
  __syncthreads();

  // Collect d <= theta_w straight from registers (no recompute, no re-read).
#pragma unroll
  for (int j = 0; j < 32; j++) {
    if (d[j] <= theta) {
      int n = 4 * tid + 1024 * (j >> 2) + (j & 3);
      int pos = atomicAdd(&cnt, 1);
      if (pos < CAP)
        cand[pos] = ((unsigned long long)__float_as_uint(d[j]) << 32) | (unsigned)n;
    }
  }
  __syncthreads();
  const int m = cnt < CAP ? cnt : CAP;

  // Exact rank by (dist_bits, idx) == stable argsort order. Keys unique.
  for (int i = tid; i < m; i += 256) {
    unsigned long long x = cand[i];
    int r = 0;
    for (int j = 0; j < m; j++) r += (cand[j] < x) ? 1 : 0;
    if (r < NS) idxOut[(size_t)q * NS + r] = (int)(unsigned)(x & 0xffffffffu);
  }
}

// ---------------- Phase 2: features (B,C,N) -> featsT (B,N,C) ----------------
__global__ __launch_bounds__(256) void transpose_kernel(const float* __restrict__ f,
                                                        float* __restrict__ ft) {
  __shared__ float t[32][33];
  const int b = blockIdx.z;
  const int n0 = blockIdx.x * 32;
  const int c0 = blockIdx.y * 32;
  const int tx = threadIdx.x;   // 0..31
  const int ty = threadIdx.y;   // 0..7
#pragma unroll
  for (int i = 0; i < 4; i++) {
    int c = c0 + ty + i * 8;
    t[ty + i * 8][tx] = f[(size_t)b * CF * NN_ + (size_t)c * NN_ + n0 + tx];
  }
  __syncthreads();
#pragma unroll
  for (int i = 0; i < 4; i++) {
    int nrow = n0 + ty + i * 8;
    ft[(size_t)b * NN_ * CF + (size_t)nrow * CF + c0 + tx] = t[tx][ty + i * 8];
  }
}

// ---------------- Phase 3: gather + grouped write ----------------
#define FSTR 68   // LDS row stride: multiple of 4 (float4 stores), 4-way alias max
__global__ __launch_bounds__(256) void group_kernel(const float* __restrict__ xyz,
                                                    const float* __restrict__ new_xyz,
                                                    const float* __restrict__ featsT,
                                                    const int* __restrict__ idxArr,
                                                    float* __restrict__ out) {
  const int q = blockIdx.x;            // b*NPOINT + p
  const int b = q / NPOINT;
  const int p = q - b * NPOINT;
  const int tid = threadIdx.x;

  __shared__ int sIdx[NS];
  __shared__ __align__(16) float ldsF[NS * FSTR];
  __shared__ float ldsX[3 * NS];

  if (tid < NS) sIdx[tid] = idxArr[q * NS + tid];
  __syncthreads();

  {
    // 256 threads = 32 samples x 8 readers; each reader pulls 32B of the
    // 256B contiguous feature row for its sample.
    int s = tid >> 3, r = tid & 7;
    int nn = sIdx[s];
    const float4* src = (const float4*)(featsT + ((size_t)b * NN_ + nn) * CF);
    float4 v0 = src[r * 2];
    float4 v1 = src[r * 2 + 1];
    float4* dst = (float4*)(ldsF + s * FSTR + r * 8);
    dst[0] = v0;
    dst[1] = v1;
  }
  if (tid < 96) {
    int dd = tid >> 5, s = tid & 31;
    int nn = sIdx[s];
    ldsX[dd * NS + s] = xyz[((size_t)b * NN_ + nn) * 3 + dd] -
                        new_xyz[(size_t)q * 3 + dd];
  }
  __syncthreads();

  // Write 67 rows of 32 floats (128B coalesced per row), 8 rows at a time.
  const int s = tid & 31;
  const int r0 = tid >> 5;
#pragma unroll
  for (int k = 0; k < 9; k++) {
    int row = r0 + k * 8;
    if (row < 67) {
      float v = (row < 3) ? ldsX[row * NS + s] : ldsF[s * FSTR + (row - 3)];
      out[(((size_t)b * 67 + row) * NPOINT + p) * NS + s] = v;
    }
  }
}

extern "C" void kernel_launch(void* const* d_in, const int* in_sizes, int n_in,
                              void* d_out, int out_size, void* d_ws, size_t ws_size,
                              hipStream_t stream) {
  const float* xyz      = (const float*)d_in[0];   // (4,8192,3)
  const float* new_xyz  = (const float*)d_in[1];   // (4,2048,3)
  // d_in[2], d_in[3]: components — unused (LAMBDA=0.5 makes mask a no-op)
  const float* features = (const float*)d_in[4];   // (4,64,8192)
  float* out = (float*)d_out;

  // workspace: [idx: 4*2048*32 int = 1MB][featsT: 4*8192*64 f32 = 8MB]
  int* idxArr = (int*)d_ws;
  float* featsT = (float*)((char*)d_ws + (size_t)BQ * NPOINT * NS * sizeof(int));

  knn_kernel<<<BQ * NPOINT, 256, 0, stream>>>(xyz, new_xyz, idxArr);
  transpose_kernel<<<dim3(NN_ / 32, CF / 32, BQ), dim3(32, 8), 0, stream>>>(features, featsT);
  group_kernel<<<BQ * NPOINT, 256, 0, stream>>>(xyz, new_xyz, featsT, idxArr, out);
}

// Round 5
// 162.663 us; speedup vs baseline: 1.7710x; 1.0781x over previous
//
#include <hip/hip_runtime.h>

// GAGKNNQueryAndGroup: B=4, N=8192, NPOINT=2048, C=64, NSAMPLE=32, LAMBDA=0.5
// LAMBDA == 0.5 makes the component mask numerically irrelevant:
// where(mask, d*0.5, d*0.5) == d*0.5 (exact, order-preserving). Components unused.
// The *0.5 itself is dropped: exact power-of-two scale, ordering (incl. ties)
// identical -> argsort indices identical.

#define BQ 4
#define NN_ 8192
#define NPOINT 2048
#define CF 64
#define NS 32
#define CAP 512   // candidate capacity (E[m]~120 with min-of-4-wave thetas)
#define FSTR 68   // LDS feature row stride (float4-aligned, bounded bank alias)

// ---------------- features (B,C,N) -> featsT (B,N,C) ----------------
__global__ __launch_bounds__(256) void transpose_kernel(const float* __restrict__ f,
                                                        float* __restrict__ ft) {
  __shared__ float t[32][33];
  const int b = blockIdx.z;
  const int n0 = blockIdx.x * 32;
  const int c0 = blockIdx.y * 32;
  const int tx = threadIdx.x;   // 0..31
  const int ty = threadIdx.y;   // 0..7
#pragma unroll
  for (int i = 0; i < 4; i++) {
    int c = c0 + ty + i * 8;
    t[ty + i * 8][tx] = f[(size_t)b * CF * NN_ + (size_t)c * NN_ + n0 + tx];
  }
  __syncthreads();
#pragma unroll
  for (int i = 0; i < 4; i++) {
    int nrow = n0 + ty + i * 8;
    ft[(size_t)b * NN_ * CF + (size_t)nrow * CF + c0 + tx] = t[tx][ty + i * 8];
  }
}

// ------- Fused: exact top-32 (round-3 proven mechanics) + group epilogue -------
__global__ __launch_bounds__(256, 3) void knn_group_kernel(
    const float* __restrict__ xyz, const float* __restrict__ new_xyz,
    const float* __restrict__ featsT, float* __restrict__ out) {
  const int q = blockIdx.x;            // b*NPOINT + p
  const int b = q >> 11;               // q / NPOINT
  const int p = q & (NPOINT - 1);
  const int tid = threadIdx.x;
  const int wave = tid >> 6;
  const int lane = tid & 63;

  __shared__ float thetas[4];
  __shared__ int cnt;
  __shared__ __align__(16) unsigned long long cand[CAP];
  __shared__ int sIdx[NS];
  __shared__ __align__(16) float ldsF[NS * FSTR];
  __shared__ float ldsX[3 * NS];

  if (tid < NS) sIdx[tid] = 0;   // defensive: no poisoned-LDS address if a slot is missed

  const float qx = new_xyz[q * 3 + 0];
  const float qy = new_xyz[q * 3 + 1];
  const float qz = new_xyz[q * 3 + 2];

  const float4* __restrict__ X4 = (const float4*)(xyz + (size_t)b * NN_ * 3);

  // ---- distance pass: thread t covers points {4t+i + 1024*jc} (round 3) ----
  float d[32];
  float lmin = 3.4e38f;
#pragma unroll
  for (int jc = 0; jc < 8; jc++) {
    float4 a0 = X4[3 * tid + 768 * jc + 0];
    float4 a1 = X4[3 * tid + 768 * jc + 1];
    float4 a2 = X4[3 * tid + 768 * jc + 2];
    float px[4] = {a0.x, a0.w, a1.z, a2.y};
    float py[4] = {a0.y, a1.x, a1.w, a2.z};
    float pz[4] = {a0.z, a1.y, a2.x, a2.w};
#pragma unroll
    for (int i = 0; i < 4; i++) {
      // exact numpy f32 semantics: no FMA contraction, left-to-right sum
      float dx = px[i] - qx;
      float dy = py[i] - qy;
      float dz = pz[i] - qz;
      float dist = __fadd_rn(__fadd_rn(__fmul_rn(dx, dx), __fmul_rn(dy, dy)),
                             __fmul_rn(dz, dz));
      d[jc * 4 + i] = dist;
      lmin = fminf(lmin, dist);
    }
  }

  // ---- per-wave theta_w: register bitonic sort of the 64 lane minima ----
  // theta_w = 32nd smallest lane-min >= true global 32nd-smallest distance
  // (the 32 smallest lane minima are 32 distinct points' distances <= theta_w).
  {
    float v = lmin;
#pragma unroll
    for (int k = 2; k <= 64; k <<= 1) {
#pragma unroll
      for (int j = k >> 1; j > 0; j >>= 1) {
        float o = __shfl_xor(v, j);
        bool dirUp = ((lane & k) == 0);
        bool lower = ((lane & j) == 0);
        float mn = fminf(v, o), mx = fmaxf(v, o);
        v = (dirUp == lower) ? mn : mx;
      }
    }
    float thw = __shfl(v, 31);          // unconditional cross-lane (round-3 form)
    if (lane == 0) thetas[wave] = thw;
  }
  if (tid == 0) cnt = 0;
  __syncthreads();
  // every theta_w is a valid global upper bound -> their min is too (tighter)
  const float theta = fminf(fminf(thetas[0], thetas[1]), fminf(thetas[2], thetas[3]));

  // ---- collect d <= theta from registers (round-3 per-lane atomic form) ----
#pragma unroll
  for (int j = 0; j < 32; j++) {
    if (d[j] <= theta) {
      int n = (tid << 2) + ((j >> 2) << 10) + (j & 3);
      int pos = atomicAdd(&cnt, 1);
      if (pos < CAP)
        cand[pos] = ((unsigned long long)__float_as_uint(d[j]) << 32) | (unsigned)n;
    }
  }
  __syncthreads();
  const int m = cnt < CAP ? cnt : CAP;

  // ---- exact rank by (dist_bits, idx) == stable argsort (round-3 form) ----
  for (int i = tid; i < m; i += 256) {
    unsigned long long x = cand[i];
    int r = 0;
    for (int j = 0; j < m; j++) r += (cand[j] < x) ? 1 : 0;
    if (r < NS) sIdx[r] = (int)(unsigned)(x & 0xffffffffu);
  }
  __syncthreads();

  // ---- group epilogue (round-1..3 proven body; sIdx now from LDS) ----
  {
    // 256 threads = 32 samples x 8 readers; 2 float4 each = 256B/sample row.
    int s = tid >> 3, rr = tid & 7;
    int nn = sIdx[s] & (NN_ - 1);   // clamp: logic bug -> absmax, not page fault
    const float4* src = (const float4*)(featsT + ((size_t)b * NN_ + nn) * CF);
    float4 v0 = src[rr * 2];
    float4 v1 = src[rr * 2 + 1];
    float4* dst = (float4*)(ldsF + s * FSTR + rr * 8);
    dst[0] = v0;
    dst[1] = v1;
  }
  if (tid < 96) {
    int dd = tid >> 5, s = tid & 31;
    int nn = sIdx[s] & (NN_ - 1);
    float qc = (dd == 0) ? qx : (dd == 1) ? qy : qz;
    ldsX[dd * NS + s] = xyz[((size_t)b * NN_ + nn) * 3 + dd] - qc;
  }
  __syncthreads();

  const int s = tid & 31;
  const int r0 = tid >> 5;
#pragma unroll
  for (int k = 0; k < 9; k++) {
    int row = r0 + k * 8;
    if (row < 67) {
      float v = (row < 3) ? ldsX[row * NS + s] : ldsF[s * FSTR + (row - 3)];
      out[(((size_t)b * 67 + row) * NPOINT + p) * NS + s] = v;
    }
  }
}

extern "C" void kernel_launch(void* const* d_in, const int* in_sizes, int n_in,
                              void* d_out, int out_size, void* d_ws, size_t ws_size,
                              hipStream_t stream) {
  const float* xyz      = (const float*)d_in[0];   // (4,8192,3)
  const float* new_xyz  = (const float*)d_in[1];   // (4,2048,3)
  // d_in[2], d_in[3]: components — unused (LAMBDA=0.5 makes mask a no-op)
  const float* features = (const float*)d_in[4];   // (4,64,8192)
  float* out = (float*)d_out;

  float* featsT = (float*)d_ws;   // 4*8192*64 f32 = 8MB

  transpose_kernel<<<dim3(NN_ / 32, CF / 32, BQ), dim3(32, 8), 0, stream>>>(features, featsT);
  knn_group_kernel<<<BQ * NPOINT, 256, 0, stream>>>(xyz, new_xyz, featsT, out);
}